// Round 10
// baseline (2945.948 us; speedup 1.0000x reference)
//
#include <hip/hip_runtime.h>
#include <cstdint>
#include <cstddef>

#define NV 50000
#define NE 300
#define NH 256
#define NR 2048
#define NL0 128
#define NLR 64
#define NS 2049      // R + 1
#define G3 768       // 3*H

// ---------------- workspace layout ----------------
static constexpr size_t alignUp(size_t x, size_t a) { return (x + a - 1) / a * a; }
static constexpr size_t OFF_CTX    = 0;                              // 256 f32 (atomicAdd target)
static constexpr size_t OFF_SCORES = OFF_CTX + 1024;                 // 2049 f32
static constexpr size_t OFF_X      = alignUp(OFF_SCORES + (size_t)NS * 4, 256);
static constexpr size_t OFF_GI_F   = alignUp(OFF_X + (size_t)NS * NE * 4, 256);
static constexpr size_t OFF_GI_B   = alignUp(OFF_GI_F + (size_t)NS * G3 * 4, 256);
static constexpr size_t OFF_OUT2   = alignUp(OFF_GI_B + (size_t)NS * G3 * 4, 256);

typedef _Float16 f16x8 __attribute__((ext_vector_type(8)));
typedef float    f32x4 __attribute__((ext_vector_type(4)));

// tanh via 1 - 2/(e^{2x}+1): exact saturation at +/-1, no NaN for finite x.
__device__ __forceinline__ float tanh_fast(float x) {
    float t = __expf(2.f * x);
    return 1.f - 2.f / (t + 1.f);
}

// ---------------- 1) X = [orig_sum ; reply_sums] ----------------
__global__ __launch_bounds__(320) void embed_sum_kernel(
    const int* __restrict__ otok, const int* __restrict__ rtok,
    const int* __restrict__ rlen, const float* __restrict__ embed,
    float* __restrict__ X)
{
    const int b = blockIdx.x;      // 0..2048
    const int e = threadIdx.x;     // < 300 active
    if (e >= NE) return;
    float acc = 0.f;
    if (b == 0) {
        for (int t = 0; t < NL0; ++t) {
            int tok = otok[t];
            acc += embed[(size_t)tok * NE + e];
        }
    } else {
        const int r = b - 1;
        const int L = rlen[r];
        const int* tr = rtok + (size_t)r * NLR;
        for (int t = 0; t < L; ++t) {
            int tok = tr[t];
            acc += embed[(size_t)tok * NE + e];
        }
    }
    X[(size_t)b * NE + e] = acc;
}

// ---------------- 2) C[M,N] = A[M,K] @ B[N,K]^T + bias[N] ----------------
__global__ __launch_bounds__(256) void gemm_abt(
    const float* __restrict__ A, const float* __restrict__ B,
    const float* __restrict__ bias, float* __restrict__ C,
    int M, int N, int K, int ldc)
{
    __shared__ float As[16][65];
    __shared__ float Bs[16][65];
    const int bm = blockIdx.x * 64, bn = blockIdx.y * 64;
    const int tid = threadIdx.x;
    const int tx = tid & 15, ty = tid >> 4;
    float acc[4][4] = {};
    for (int k0 = 0; k0 < K; k0 += 16) {
        #pragma unroll
        for (int i = 0; i < 4; ++i) {
            int l = tid + 256 * i;
            int mm = l >> 4, kk = l & 15;
            int gm = bm + mm, gk = k0 + kk;
            As[kk][mm] = (gm < M && gk < K) ? A[(size_t)gm * K + gk] : 0.f;
            int gn = bn + mm;
            Bs[kk][mm] = (gk < K) ? B[(size_t)gn * K + gk] : 0.f;
        }
        __syncthreads();
        #pragma unroll
        for (int kk = 0; kk < 16; ++kk) {
            float a0 = As[kk][ty], a1 = As[kk][ty+16], a2 = As[kk][ty+32], a3 = As[kk][ty+48];
            float b0 = Bs[kk][tx], b1 = Bs[kk][tx+16], b2 = Bs[kk][tx+32], b3 = Bs[kk][tx+48];
            acc[0][0] += a0*b0; acc[0][1] += a0*b1; acc[0][2] += a0*b2; acc[0][3] += a0*b3;
            acc[1][0] += a1*b0; acc[1][1] += a1*b1; acc[1][2] += a1*b2; acc[1][3] += a1*b3;
            acc[2][0] += a2*b0; acc[2][1] += a2*b1; acc[2][2] += a2*b2; acc[2][3] += a2*b3;
            acc[3][0] += a3*b0; acc[3][1] += a3*b1; acc[3][2] += a3*b2; acc[3][3] += a3*b3;
        }
        __syncthreads();
    }
    #pragma unroll
    for (int i = 0; i < 4; ++i) {
        int gm = bm + ty + 16 * i;
        if (gm >= M) continue;
        #pragma unroll
        for (int j = 0; j < 4; ++j) {
            int gn = bn + tx + 16 * j;
            C[(size_t)gm * ldc + gn] = acc[i][j] + bias[gn];
        }
    }
}

// ---------------- 3) bidirectional GRU recurrence: MFMA matvec ----------------
// 2 blocks x 512 threads (8 waves), one per direction; each direction on ONE CU.
//
// 9-round register war conclusion: the allocator ALWAYS places the 192-dword
// weight array in AGPRs, and v_dot2 can't read AGPRs -> ~192 v_accvgpr_read per
// wave per step (~60% of VALU issue). MFMA *can* read A/B/C/D from AGPRs on
// gfx950 (unified file, ISA sec.10) -- so compute gh = Whh @ h on the MATRIX
// pipe with weights deliberately AGPR-resident:
//   y[768] = W[768x256]*h: 48 row-tiles(16) x 8 k-tiles(32), mfma_f32_16x16x32_f16.
//   wave w owns tiles w*6..w*6+5: A-fragments = 48 x f16x8 = 192 dwords, staged once.
//   B = h broadcast to all 16 cols: lane reads hl16[kt*32+(lane>>4)*8 ..+7]
//   (ds_read_b128, 16-lane broadcast, conflict-free). A and B staged with the
//   SAME k-indexing k=(lane>>4)*8+j => contraction correct for ANY hw k-order
//   (permutation invariance; B's columns identical). A row = lane&15 (standard);
//   D: col=lane&15, row=(lane>>4)*4+reg (HW-verified mapping) -> lanes with
//   lane&15==0 write f32x4 rows to y in LDS.
// Gates: thread e (=tid<256) keeps h[e] in-register (f32 exact), reads y from
// LDS, adds gi (prefetched) + bhh, sigmoid/tanh, writes f16 shadow h for next
// step. 2 barriers/step. out2 store deferred one step (r8 win, kept).
__global__ __launch_bounds__(512) void gru_kernel(
    const float* __restrict__ Whh_f, const float* __restrict__ bhh_f,
    const float* __restrict__ Whh_b, const float* __restrict__ bhh_b,
    const float* __restrict__ gi_f, const float* __restrict__ gi_b,
    float* __restrict__ out2)
{
    const int dir  = blockIdx.x;
    const int tid  = threadIdx.x;
    const int lane = tid & 63;
    const int wave = tid >> 6;          // 0..7
    const int lg   = lane >> 4;         // k-group 0..3
    const int lr   = lane & 15;         // A row within tile / D col

    const float* __restrict__ Whh = dir ? Whh_b : Whh_f;
    const float* __restrict__ bhh = dir ? bhh_b : bhh_f;
    const float* __restrict__ gi  = dir ? gi_b  : gi_f;

    __shared__ __align__(16) _Float16 hl16[2][NH];   // f16 h (dot operand), dbuf
    __shared__ __align__(16) float    ysh[G3];       // gh results (MFMA D)

    if (tid < NH) hl16[0][tid] = (_Float16)0.f;

    // ---- stage A-fragments: wA[i][kt] = W[16*(wave*6+i)+lr][kt*32 + lg*8 + j] ----
    f16x8 wA[6][8];
    {
        #pragma unroll
        for (int i = 0; i < 6; ++i) {
            const float* rowp = Whh + (size_t)((wave * 6 + i) * 16 + lr) * NH + lg * 8;
            #pragma unroll
            for (int kt = 0; kt < 8; ++kt) {
                float4 a = *(const float4*)(rowp + kt * 32);
                float4 b = *(const float4*)(rowp + kt * 32 + 4);
                f16x8 w;
                w[0] = (_Float16)a.x; w[1] = (_Float16)a.y;
                w[2] = (_Float16)a.z; w[3] = (_Float16)a.w;
                w[4] = (_Float16)b.x; w[5] = (_Float16)b.y;
                w[6] = (_Float16)b.z; w[7] = (_Float16)b.w;
                wA[i][kt] = w;
                __builtin_amdgcn_sched_barrier(0);   // cap staging pressure peak (r8)
            }
        }
    }

    // ---- gate-thread state (tid < 256: element e = tid) ----
    const bool isGate = (tid < NH);
    const int  e = tid;
    float bhr = 0.f, bhz = 0.f, bhn = 0.f;
    float gir = 0.f, giz = 0.f, gin = 0.f;
    float hreg = 0.f;                    // exact f32 h[e] carried in-register
    float hnPend = 0.f;
    int   offPend = 0;
    if (isGate) {
        bhr = bhh[e]; bhz = bhh[NH + e]; bhn = bhh[2 * NH + e];
        const float* g0 = gi + (size_t)(dir ? NS - 1 : 0) * G3 + e;
        gir = g0[0]; giz = g0[NH]; gin = g0[2 * NH];
    }
    __syncthreads();

    for (int t = 0; t < NS; ++t) {
        const int p = t & 1;
        const int s = dir ? (NS - 1 - t) : t;

        // flush previous step's out2 (has the whole step to retire before S1)
        if (isGate && t > 0) out2[offPend] = hnPend;

        // prefetch next step's gi (consumed after S1; hides L2 latency)
        float girN = 0.f, gizN = 0.f, ginN = 0.f;
        if (isGate && t < NS - 1) {
            const float* gn = gi + (size_t)(dir ? (NS - 2 - t) : (t + 1)) * G3 + e;
            girN = gn[0]; gizN = gn[NH]; ginN = gn[2 * NH];
        }

        // ---- MFMA phase: 6 tiles in 2 groups of 3 (saves acc regs) ----
        const _Float16* hp = &hl16[p][0];
        #pragma unroll
        for (int grp = 0; grp < 2; ++grp) {
            f32x4 a0 = {0.f, 0.f, 0.f, 0.f};
            f32x4 a1 = {0.f, 0.f, 0.f, 0.f};
            f32x4 a2 = {0.f, 0.f, 0.f, 0.f};
            #pragma unroll
            for (int kt = 0; kt < 8; ++kt) {
                uint4 u = *(const uint4*)(hp + kt * 32 + lg * 8);   // broadcast b128
                f16x8 hb = __builtin_bit_cast(f16x8, u);
                a0 = __builtin_amdgcn_mfma_f32_16x16x32_f16(wA[grp*3+0][kt], hb, a0, 0, 0, 0);
                a1 = __builtin_amdgcn_mfma_f32_16x16x32_f16(wA[grp*3+1][kt], hb, a1, 0, 0, 0);
                a2 = __builtin_amdgcn_mfma_f32_16x16x32_f16(wA[grp*3+2][kt], hb, a2, 0, 0, 0);
            }
            if (lr == 0) {   // D: col=lane&15, row=(lane>>4)*4+reg -> 4 lanes/wave
                *(f32x4*)(&ysh[(wave * 6 + grp * 3 + 0) * 16 + lg * 4]) = a0;
                *(f32x4*)(&ysh[(wave * 6 + grp * 3 + 1) * 16 + lg * 4]) = a1;
                *(f32x4*)(&ysh[(wave * 6 + grp * 3 + 2) * 16 + lg * 4]) = a2;
            }
        }
        __syncthreads();   // S1: ysh ready

        // ---- gate phase ----
        if (isGate) {
            const float yr = ysh[e], yz = ysh[NH + e], yn = ysh[2 * NH + e];
            const float r  = 1.f / (1.f + __expf(-(gir + yr + bhr)));
            const float z  = 1.f / (1.f + __expf(-(giz + yz + bhz)));
            const float n  = tanh_fast(gin + r * (yn + bhn));
            const float hn = (1.f - z) * n + z * hreg;
            hreg = hn;
            hl16[p ^ 1][e] = (_Float16)hn;
            hnPend  = hn;
            offPend = s * (2 * NH) + dir * NH + e;
            gir = girN; giz = gizN; gin = ginN;
        }
        __syncthreads();   // S2: h(t+1) shadow ready; ysh reusable
    }
    if (isGate) out2[offPend] = hnPend;   // flush last step
}

// ---------------- 4) scores[s] = dot(output[s], h_f + h_b) ----------------
__global__ __launch_bounds__(256) void scores_kernel(
    const float* __restrict__ outp, const float* __restrict__ out2,
    float* __restrict__ scores)
{
    const int s = blockIdx.x, m = threadIdx.x;
    float hs = out2[(size_t)(NS - 1) * (2 * NH) + m] + out2[NH + m];
    float v = outp[(size_t)s * NH + m] * hs;
    #pragma unroll
    for (int o = 32; o > 0; o >>= 1) v += __shfl_down(v, o);
    __shared__ float p[4];
    if ((m & 63) == 0) p[m >> 6] = v;
    __syncthreads();
    if (m == 0) scores[s] = p[0] + p[1] + p[2] + p[3];
}

// ---------------- 5) softmax over 2049 scores (in place) ----------------
__global__ __launch_bounds__(1024) void softmax_kernel(float* __restrict__ sc)
{
    const int tid = threadIdx.x;
    __shared__ float red[16];
    float x0 = (tid < NS) ? sc[tid] : -3.0e38f;
    float x1 = (tid + 1024 < NS) ? sc[tid + 1024] : -3.0e38f;
    float mx = fmaxf(x0, x1);
    #pragma unroll
    for (int o = 32; o > 0; o >>= 1) mx = fmaxf(mx, __shfl_xor(mx, o));
    if ((tid & 63) == 0) red[tid >> 6] = mx;
    __syncthreads();
    if (tid == 0) {
        float m = red[0];
        for (int i = 1; i < 16; ++i) m = fmaxf(m, red[i]);
        red[0] = m;
    }
    __syncthreads();
    const float gmax = red[0];
    float e0 = (tid < NS) ? __expf(x0 - gmax) : 0.f;
    float e1 = (tid + 1024 < NS) ? __expf(x1 - gmax) : 0.f;
    float sm = e0 + e1;
    #pragma unroll
    for (int o = 32; o > 0; o >>= 1) sm += __shfl_xor(sm, o);
    __syncthreads();
    if ((tid & 63) == 0) red[tid >> 6] = sm;
    __syncthreads();
    if (tid == 0) {
        float su = 0.f;
        for (int i = 0; i < 16; ++i) su += red[i];
        red[1] = 1.f / su;
    }
    __syncthreads();
    const float inv = red[1];
    if (tid < NS) sc[tid] = e0 * inv;
    if (tid + 1024 < NS) sc[tid + 1024] = e1 * inv;
}

// ---------------- 6) ctx[m] += sum_s w[s]*output[s][m] (partial per block) ----------------
__global__ __launch_bounds__(256) void ctx_kernel(
    const float* __restrict__ outp, const float* __restrict__ w,
    float* __restrict__ ctx)
{
    const int m = threadIdx.x;
    const int s0 = blockIdx.x * 128;
    const int s1 = min(s0 + 128, NS);
    float acc = 0.f;
    for (int s = s0; s < s1; ++s) acc += w[s] * outp[(size_t)s * NH + m];
    atomicAdd(&ctx[m], acc);
}

// ---------------- 7) result + loss ----------------
__global__ __launch_bounds__(256) void final_kernel(
    const float* __restrict__ ctx, const float* __restrict__ Wo,
    const float* __restrict__ bo, const float* __restrict__ label,
    float* __restrict__ dout)
{
    const int m = threadIdx.x;
    float v = ctx[m] * Wo[m];
    #pragma unroll
    for (int o = 32; o > 0; o >>= 1) v += __shfl_down(v, o);
    __shared__ float p[4];
    if ((m & 63) == 0) p[m >> 6] = v;
    __syncthreads();
    if (m == 0) {
        float x = p[0] + p[1] + p[2] + p[3] + bo[0];
        float result = 1.f / (1.f + __expf(-x));
        float d = label[0] - result;
        dout[(size_t)NS * NH]     = d * d;
        dout[(size_t)NS * NH + 1] = result;
    }
}

extern "C" void kernel_launch(void* const* d_in, const int* in_sizes, int n_in,
                              void* d_out, int out_size, void* d_ws, size_t ws_size,
                              hipStream_t stream)
{
    const int*   otok  = (const int*)d_in[0];
    const int*   rtok  = (const int*)d_in[1];
    const int*   rlen  = (const int*)d_in[2];
    const float* label = (const float*)d_in[3];
    const float* embed = (const float*)d_in[4];
    const float* Wih_f = (const float*)d_in[5];
    const float* Whh_f = (const float*)d_in[6];
    const float* bih_f = (const float*)d_in[7];
    const float* bhh_f = (const float*)d_in[8];
    const float* Wih_b = (const float*)d_in[9];
    const float* Whh_b = (const float*)d_in[10];
    const float* bih_b = (const float*)d_in[11];
    const float* bhh_b = (const float*)d_in[12];
    const float* Wl    = (const float*)d_in[13];
    const float* bl    = (const float*)d_in[14];
    const float* Wo    = (const float*)d_in[15];
    const float* bo    = (const float*)d_in[16];

    char* ws = (char*)d_ws;
    float* ctx    = (float*)(ws + OFF_CTX);
    float* scores = (float*)(ws + OFF_SCORES);
    float* X      = (float*)(ws + OFF_X);
    float* gi_f   = (float*)(ws + OFF_GI_F);
    float* gi_b   = (float*)(ws + OFF_GI_B);
    float* out2   = (float*)(ws + OFF_OUT2);
    float* outp   = (float*)d_out;   // first 2049*256 floats = `output`

    // zero ctx accumulator (graph-capture-safe)
    hipMemsetAsync(ws + OFF_CTX, 0, 1024, stream);

    // 1) embedding sums
    embed_sum_kernel<<<NS, 320, 0, stream>>>(otok, rtok, rlen, embed, X);

    // 2) input-gate pre-GEMMs: gi = X @ Wih^T + bih  (both directions)
    gemm_abt<<<dim3(33, 12), 256, 0, stream>>>(X, Wih_f, bih_f, gi_f, NS, G3, NE, G3);
    gemm_abt<<<dim3(33, 12), 256, 0, stream>>>(X, Wih_b, bih_b, gi_b, NS, G3, NE, G3);

    // 3) recurrence: one self-contained CU per direction (no inter-WG traffic)
    gru_kernel<<<2, 512, 0, stream>>>(Whh_f, bhh_f, Whh_b, bhh_b,
                                      gi_f, gi_b, out2);

    // 4) output = out2 @ Wl^T + bl  -> d_out
    gemm_abt<<<dim3(33, 4), 256, 0, stream>>>(out2, Wl, bl, outp, NS, NH, 2 * NH, NH);

    // 5) attention + head
    scores_kernel<<<NS, 256, 0, stream>>>(outp, out2, scores);
    softmax_kernel<<<1, 1024, 0, stream>>>(scores);
    ctx_kernel<<<(NS + 127) / 128, 256, 0, stream>>>(outp, scores, ctx);
    final_kernel<<<1, 256, 0, stream>>>(ctx, Wo, bo, label, (float*)d_out);
}